// Round 1
// baseline (234.224 us; speedup 1.0000x reference)
//
#include <hip/hip_runtime.h>
#include <hip/hip_bf16.h>

#define B_   8
#define H_   256
#define L_   4096
#define N2_  32
#define CH_  64     // chunks per row == threads per block (kernel 1)
#define TT_  64     // timesteps per chunk

__device__ __forceinline__ int upad(int i) { return i + (i >> 6); }  // stride 64 -> 65

// ---------------------------------------------------------------------------
// Kernel 1: S4D recurrence via chunked scan, + D-skip + exact GELU -> bf16 ws
// grid = B*H blocks of 64 threads; each thread owns one 64-step chunk and all
// 32 complex states in registers.
// ---------------------------------------------------------------------------
__global__ __launch_bounds__(64) void s4_scan_kernel(
    const float* __restrict__ u,
    const float* __restrict__ log_dt,
    const float* __restrict__ log_A_real,
    const float* __restrict__ A_imag,
    const float* __restrict__ C_re,
    const float* __restrict__ C_im,
    const float* __restrict__ Dp,
    __hip_bfloat16* __restrict__ Gout)
{
    __shared__ float su[L_ + (L_ >> 6)];     // 4160 floats, padded (16.6 KB)
    __shared__ float sSr[N2_ * 65];          // chunk states re, [n*65 + c]
    __shared__ float sSi[N2_ * 65];          // chunk states im
    __shared__ float sPar[6][N2_];           // wr, wi, ckr, cki, wTr, wTi

    const int bh  = blockIdx.x;
    const int h   = bh & (H_ - 1);
    const int tid = threadIdx.x;
    const float* __restrict__ urow = u + (size_t)bh * L_;

    // ---- stage u row into padded LDS (coalesced float4 global loads) ----
    {
        const float4* u4 = (const float4*)urow;
        #pragma unroll
        for (int it = 0; it < (L_ / 4 / CH_); ++it) {   // 16 iters
            int q = it * CH_ + tid;
            float4 v = u4[q];
            int p = upad(q * 4);                         // stays within chunk
            su[p + 0] = v.x; su[p + 1] = v.y; su[p + 2] = v.z; su[p + 3] = v.w;
        }
    }

    // ---- per-n parameters (threads 0..31), shared via LDS ----
    if (tid < N2_) {
        int n = tid;
        float dt = expf(log_dt[h]);
        float Ar = -expf(log_A_real[h * N2_ + n]);
        float Ai = A_imag[h * N2_ + n];
        float er = expf(dt * Ar);
        float s, c;
        sincosf(dt * Ai, &s, &c);                        // precise: error compounds x4096
        float wr = er * c, wi = er * s;
        float cr = C_re[h * N2_ + n], ci = C_im[h * N2_ + n];
        // (w-1)/A
        float den = Ar * Ar + Ai * Ai;
        float nr = wr - 1.0f, ni = wi;
        float qr = (nr * Ar + ni * Ai) / den;
        float qi = (ni * Ar - nr * Ai) / den;
        float ckr = cr * qr - ci * qi;
        float cki = cr * qi + ci * qr;
        // w^64 by squaring
        float pr = wr, pi = wi;
        #pragma unroll
        for (int k = 0; k < 6; ++k) { float tr2 = pr*pr - pi*pi; float ti2 = 2.0f*pr*pi; pr = tr2; pi = ti2; }
        sPar[0][n] = wr;  sPar[1][n] = wi;
        sPar[2][n] = ckr; sPar[3][n] = cki;
        sPar[4][n] = pr;  sPar[5][n] = pi;
    }
    __syncthreads();

    // ---- broadcast params into per-thread register arrays (static idx) ----
    float wr[N2_], wi[N2_], kr[N2_], ki[N2_];
    #pragma unroll
    for (int n = 0; n < N2_; ++n) {
        wr[n] = sPar[0][n]; wi[n] = sPar[1][n];
        kr[n] = sPar[2][n]; ki[n] = sPar[3][n];
    }

    // ---- pass A: chunk-local recurrence from zero state ----
    float xr[N2_], xi[N2_];
    #pragma unroll
    for (int n = 0; n < N2_; ++n) { xr[n] = 0.0f; xi[n] = 0.0f; }
    const float halfD = 0.5f * Dp[h];
    const int base = tid * TT_;

    float uu = su[upad(base)];
    #pragma unroll 1
    for (int j = 0; j < TT_; ++j) {
        float un = (j + 1 < TT_) ? su[upad(base + j + 1)] : 0.0f;  // prefetch
        float ac[4];
        ac[0] = halfD * uu; ac[1] = 0.0f; ac[2] = 0.0f; ac[3] = 0.0f;
        #pragma unroll
        for (int n = 0; n < N2_; ++n) {
            float nxr = fmaf(wr[n], xr[n], fmaf(-wi[n], xi[n], uu));
            float nxi = fmaf(wi[n], xr[n], wr[n] * xi[n]);
            xr[n] = nxr; xi[n] = nxi;
            ac[n & 3] = fmaf(kr[n], nxr, fmaf(-ki[n], nxi, ac[n & 3]));
        }
        su[upad(base + j)] = (ac[0] + ac[1]) + (ac[2] + ac[3]);
        uu = un;
    }
    #pragma unroll
    for (int n = 0; n < N2_; ++n) {
        sSr[n * 65 + tid] = xr[n];
        sSi[n * 65 + tid] = xi[n];
    }
    __syncthreads();

    // ---- serial scan over chunks (one thread per n); leaves INCOMING state ----
    if (tid < N2_) {
        int n = tid;
        float aTr = sPar[4][n], aTi = sPar[5][n];
        float Xr = 0.0f, Xi = 0.0f;
        #pragma unroll 1
        for (int c = 0; c < CH_; ++c) {
            float sr = sSr[n * 65 + c];
            float si = sSi[n * 65 + c];
            sSr[n * 65 + c] = Xr;
            sSi[n * 65 + c] = Xi;
            float nXr = fmaf(aTr, Xr, fmaf(-aTi, Xi, sr));
            float nXi = fmaf(aTi, Xr, fmaf(aTr, Xi, si));
            Xr = nXr; Xi = nXi;
        }
    }
    __syncthreads();

    // ---- pass B: add Re(Ck * X * w^{j+1}) correction, GELU, store to su ----
    float gr[N2_], gi[N2_];
    #pragma unroll
    for (int n = 0; n < N2_; ++n) {
        float Xr = sSr[n * 65 + tid];
        float Xi = sSi[n * 65 + tid];
        gr[n] = kr[n] * Xr - ki[n] * Xi;
        gi[n] = kr[n] * Xi + ki[n] * Xr;
    }
    float aa = su[upad(base)];
    #pragma unroll 1
    for (int j = 0; j < TT_; ++j) {
        float an = (j + 1 < TT_) ? su[upad(base + j + 1)] : 0.0f;
        float co[4];
        co[0] = 0.0f; co[1] = 0.0f; co[2] = 0.0f; co[3] = 0.0f;
        #pragma unroll
        for (int n = 0; n < N2_; ++n) {
            float ngr = fmaf(gr[n], wr[n], -gi[n] * wi[n]);
            float ngi = fmaf(gr[n], wi[n],  gi[n] * wr[n]);
            gr[n] = ngr; gi[n] = ngi;
            co[n & 3] += ngr;
        }
        float y = 2.0f * (aa + ((co[0] + co[1]) + (co[2] + co[3])));
        float ge = 0.5f * y * (1.0f + erff(y * 0.70710678118654752f));
        su[upad(base + j)] = ge;
        aa = an;
    }
    __syncthreads();

    // ---- coalesced bf16 store of GELU output ----
    {
        __hip_bfloat16* __restrict__ grow = Gout + (size_t)bh * L_;
        #pragma unroll 1
        for (int it = 0; it < 8; ++it) {
            int i = it * (CH_ * 8) + tid * 8;
            int p = upad(i);
            union { __hip_bfloat16 hv[8]; uint4 v; } pk;
            #pragma unroll
            for (int t = 0; t < 8; ++t) pk.hv[t] = __float2bfloat16(su[p + t]);
            *(uint4*)&grow[i] = pk.v;
        }
    }
}

// ---------------------------------------------------------------------------
// Kernel 2: out = (Wa*G + ba) * sigmoid(Wg*G + bg), fused GLU epilogue.
// Block tile: 64 op-pairs x 128 l. 256 threads, 64 acc each. K tiled by 32.
// ---------------------------------------------------------------------------
#define OPT_ 64
#define LT_  128
#define KT_  32

__global__ __launch_bounds__(256) void glu_gemm_kernel(
    const __hip_bfloat16* __restrict__ G,
    const float* __restrict__ W,
    const float* __restrict__ bo,
    float* __restrict__ out)
{
    __shared__ float sWa[KT_][OPT_];
    __shared__ float sWg[KT_][OPT_];
    __shared__ __hip_bfloat16 sG[KT_][LT_];

    const int lt  = blockIdx.x;           // 0..255
    const int b   = lt >> 5;
    const int l0  = (lt & 31) * LT_;
    const int op0 = blockIdx.y * OPT_;

    const int tid = threadIdx.x;
    const int tr  = tid >> 4;             // 0..15 -> op group
    const int tc  = tid & 15;             // 0..15 -> l group
    const int opB = tr * 4;
    const int lB  = tc * 8;

    float accA[4][8], accG[4][8];
    #pragma unroll
    for (int i = 0; i < 4; ++i)
        #pragma unroll
        for (int j = 0; j < 8; ++j) { accA[i][j] = 0.0f; accG[i][j] = 0.0f; }

    const int wRow = tid & 63;
    const int wSeg = tid >> 6;            // 0..3
    const int gRow = tid >> 4;            // 0..15
    const int gCol = (tid & 15) * 8;

    for (int k0 = 0; k0 < H_; k0 += KT_) {
        __syncthreads();
        // stage W tiles (transposed to [k][op])
        {
            const float* pa = W + (size_t)(op0 + wRow) * H_ + k0 + wSeg * 8;
            float4 a0 = *(const float4*)pa;
            float4 a1 = *(const float4*)(pa + 4);
            const float* pg = W + (size_t)(op0 + wRow + 256) * H_ + k0 + wSeg * 8;
            float4 g0 = *(const float4*)pg;
            float4 g1 = *(const float4*)(pg + 4);
            int kb = wSeg * 8;
            sWa[kb+0][wRow]=a0.x; sWa[kb+1][wRow]=a0.y; sWa[kb+2][wRow]=a0.z; sWa[kb+3][wRow]=a0.w;
            sWa[kb+4][wRow]=a1.x; sWa[kb+5][wRow]=a1.y; sWa[kb+6][wRow]=a1.z; sWa[kb+7][wRow]=a1.w;
            sWg[kb+0][wRow]=g0.x; sWg[kb+1][wRow]=g0.y; sWg[kb+2][wRow]=g0.z; sWg[kb+3][wRow]=g0.w;
            sWg[kb+4][wRow]=g1.x; sWg[kb+5][wRow]=g1.y; sWg[kb+6][wRow]=g1.z; sWg[kb+7][wRow]=g1.w;
        }
        // stage G tile [k][l] (bf16, coalesced 16B loads)
        #pragma unroll
        for (int r2 = 0; r2 < 2; ++r2) {
            int r = r2 * 16 + gRow;
            const __hip_bfloat16* gp = G + ((size_t)(b * H_ + k0 + r)) * L_ + l0 + gCol;
            *(uint4*)&sG[r][gCol] = *(const uint4*)gp;
        }
        __syncthreads();

        #pragma unroll 4
        for (int kk = 0; kk < KT_; ++kk) {
            float4 wa = *(const float4*)&sWa[kk][opB];
            float4 wg = *(const float4*)&sWg[kk][opB];
            uint4 gv = *(const uint4*)&sG[kk][lB];
            float act[8];
            act[0] = __uint_as_float(gv.x << 16);
            act[1] = __uint_as_float(gv.x & 0xffff0000u);
            act[2] = __uint_as_float(gv.y << 16);
            act[3] = __uint_as_float(gv.y & 0xffff0000u);
            act[4] = __uint_as_float(gv.z << 16);
            act[5] = __uint_as_float(gv.z & 0xffff0000u);
            act[6] = __uint_as_float(gv.w << 16);
            act[7] = __uint_as_float(gv.w & 0xffff0000u);
            const float* waf = (const float*)&wa;
            const float* wgf = (const float*)&wg;
            #pragma unroll
            for (int i = 0; i < 4; ++i) {
                float av = waf[i], gvv = wgf[i];
                #pragma unroll
                for (int j = 0; j < 8; ++j) {
                    accA[i][j] = fmaf(av,  act[j], accA[i][j]);
                    accG[i][j] = fmaf(gvv, act[j], accG[i][j]);
                }
            }
        }
    }

    // ---- GLU epilogue + coalesced store ----
    #pragma unroll
    for (int i = 0; i < 4; ++i) {
        int op = op0 + opB + i;
        float ba = bo[op];
        float bg = bo[op + 256];
        float res[8];
        #pragma unroll
        for (int j = 0; j < 8; ++j) {
            float a = accA[i][j] + ba;
            float g = accG[i][j] + bg;
            float sg = 1.0f / (1.0f + expf(-g));
            res[j] = a * sg;
        }
        float* po = out + (size_t)(b * H_ + op) * L_ + l0 + lB;
        *(float4*)po       = make_float4(res[0], res[1], res[2], res[3]);
        *(float4*)(po + 4) = make_float4(res[4], res[5], res[6], res[7]);
    }
}

extern "C" void kernel_launch(void* const* d_in, const int* in_sizes, int n_in,
                              void* d_out, int out_size, void* d_ws, size_t ws_size,
                              hipStream_t stream) {
    (void)in_sizes; (void)n_in; (void)out_size;
    const float* hs     = (const float*)d_in[0];
    const float* log_dt = (const float*)d_in[1];
    const float* logA   = (const float*)d_in[2];
    const float* Aim    = (const float*)d_in[3];
    const float* Cre    = (const float*)d_in[4];
    const float* Cim    = (const float*)d_in[5];
    const float* Dp     = (const float*)d_in[6];
    const float* Wout   = (const float*)d_in[7];
    const float* bout   = (const float*)d_in[8];
    float* out          = (float*)d_out;
    __hip_bfloat16* G   = (__hip_bfloat16*)d_ws;

    if (ws_size < (size_t)B_ * H_ * L_ * sizeof(__hip_bfloat16)) return;

    s4_scan_kernel<<<dim3(B_ * H_), dim3(64), 0, stream>>>(
        hs, log_dt, logA, Aim, Cre, Cim, Dp, G);
    glu_gemm_kernel<<<dim3(256, 4), dim3(256), 0, stream>>>(
        G, Wout, bout, out);
}

// Round 2
// 127.594 us; speedup vs baseline: 1.8357x; 1.8357x over previous
//
#include <hip/hip_runtime.h>
#include <hip/hip_bf16.h>

#define B_   8
#define H_   256
#define L_   4096
#define N2_  32

typedef __attribute__((ext_vector_type(8))) short bf16x8;
typedef __attribute__((ext_vector_type(4))) float f32x4;

__device__ __forceinline__ unsigned short f2bf(float x) {
    __hip_bfloat16 h = __float2bfloat16(x);
    unsigned short us;
    __builtin_memcpy(&us, &h, 2);
    return us;
}

// ---------------------------------------------------------------------------
// Kernel 1: S4D recurrence via chunked scan (fused recompute), D-skip + GELU.
// 4 heads per block (1 wave each, 256 thr). Each lane owns one 64-step chunk
// with all 32 complex states in registers. Pass A: end-states only. Serial
// per-n scan. Pass B: recompute from incoming state, emit y directly.
// Output G stored bf16 in transposed-blocked layout [b][h>>2][l][h&3] so the
// GEMM can load k-major fragments contiguously.
// ---------------------------------------------------------------------------
__global__ __launch_bounds__(256, 2) void s4_scan_kernel(
    const float* __restrict__ u,
    const float* __restrict__ log_dt,
    const float* __restrict__ log_A_real,
    const float* __restrict__ A_imag,
    const float* __restrict__ C_re,
    const float* __restrict__ C_im,
    const float* __restrict__ Dp,
    unsigned short* __restrict__ Gout)
{
    __shared__ float sS[4 * 64 * 65];        // 66560 B; overlaid by ybuf later
    __shared__ float sPar[4][6][32];

    const int tid = threadIdx.x;
    const int w   = tid >> 6;                // wave -> head within group
    const int c   = tid & 63;                // chunk index
    const int bid = blockIdx.x;              // 512 blocks
    const int b   = bid >> 6;
    const int hg  = bid & 63;
    const int h   = hg * 4 + w;

    const float* __restrict__ urow = u + ((size_t)(b * H_ + h)) * L_;

    if (c < 32) {
        int n = c;
        float dt = expf(log_dt[h]);
        float Ar = -expf(log_A_real[h * N2_ + n]);
        float Ai = A_imag[h * N2_ + n];
        float er = expf(dt * Ar);
        float s, co;
        sincosf(dt * Ai, &s, &co);           // precise: phase error compounds x4096
        float wrv = er * co, wiv = er * s;
        float cr = C_re[h * N2_ + n], ci = C_im[h * N2_ + n];
        float den = Ar * Ar + Ai * Ai;
        float nr = wrv - 1.0f, ni = wiv;
        float qr = (nr * Ar + ni * Ai) / den;
        float qi = (ni * Ar - nr * Ai) / den;
        sPar[w][0][n] = wrv;
        sPar[w][1][n] = wiv;
        sPar[w][2][n] = cr * qr - ci * qi;   // Ck re
        sPar[w][3][n] = cr * qi + ci * qr;   // Ck im
        float pr = wrv, pi = wiv;            // w^64 by squaring
        #pragma unroll
        for (int k = 0; k < 6; ++k) { float a2 = pr*pr - pi*pi, b2 = 2.0f*pr*pi; pr = a2; pi = b2; }
        sPar[w][4][n] = pr;
        sPar[w][5][n] = pi;
    }
    __syncthreads();

    float wr[N2_], wi[N2_];
    #pragma unroll
    for (int n = 0; n < N2_; ++n) { wr[n] = sPar[w][0][n]; wi[n] = sPar[w][1][n]; }

    // ---- pass A: chunk-local end-states only ----
    float xr[N2_], xi[N2_];
    #pragma unroll
    for (int n = 0; n < N2_; ++n) { xr[n] = 0.0f; xi[n] = 0.0f; }

    const float4* u4 = (const float4*)(urow + c * 64);
    float4 ub = u4[0];
    #pragma unroll 1
    for (int q = 0; q < 16; ++q) {
        float4 un = (q < 15) ? u4[q + 1] : ub;
        #pragma unroll
        for (int s = 0; s < 4; ++s) {
            float uu = ((const float*)&ub)[s];
            #pragma unroll
            for (int n = 0; n < N2_; ++n) {
                float nxr = fmaf(wr[n], xr[n], fmaf(-wi[n], xi[n], uu));
                float nxi = fmaf(wi[n], xr[n], wr[n] * xi[n]);
                xr[n] = nxr; xi[n] = nxi;
            }
        }
        ub = un;
    }
    #pragma unroll
    for (int n = 0; n < N2_; ++n) {
        sS[(w * 64 + n) * 65 + c]      = xr[n];
        sS[(w * 64 + 32 + n) * 65 + c] = xi[n];
    }
    __syncthreads();

    // ---- serial scan over chunks (lanes 0..31 per wave); leaves INCOMING state
    if (c < 32) {
        int n = c;
        float aTr = sPar[w][4][n], aTi = sPar[w][5][n];
        float Xr = 0.0f, Xi = 0.0f;
        float* pr = &sS[(w * 64 + n) * 65];
        float* pi = &sS[(w * 64 + 32 + n) * 65];
        #pragma unroll 4
        for (int cc = 0; cc < 64; ++cc) {
            float sr = pr[cc], si = pi[cc];
            pr[cc] = Xr; pi[cc] = Xi;
            float nXr = fmaf(aTr, Xr, fmaf(-aTi, Xi, sr));
            float nXi = fmaf(aTi, Xr, fmaf(aTr, Xi, si));
            Xr = nXr; Xi = nXi;
        }
    }
    __syncthreads();

    #pragma unroll
    for (int n = 0; n < N2_; ++n) {
        xr[n] = sS[(w * 64 + n) * 65 + c];
        xi[n] = sS[(w * 64 + 32 + n) * 65 + c];
    }
    __syncthreads();   // states consumed; safe to overlay ybuf on sS

    float kr[N2_], ki[N2_];
    #pragma unroll
    for (int n = 0; n < N2_; ++n) { kr[n] = sPar[w][2][n]; ki[n] = sPar[w][3][n]; }

    // ---- pass B: recompute recurrence from incoming state, emit y ----
    unsigned short* ybuf = (unsigned short*)sS;      // [w][j*65 + c] bf16
    const float halfD = 0.5f * Dp[h];
    ub = u4[0];
    #pragma unroll 1
    for (int q = 0; q < 16; ++q) {
        float4 un = (q < 15) ? u4[q + 1] : ub;
        #pragma unroll
        for (int s = 0; s < 4; ++s) {
            float uu = ((const float*)&ub)[s];
            float acm[4] = {halfD * uu, 0.0f, 0.0f, 0.0f};
            #pragma unroll
            for (int n = 0; n < N2_; ++n) {
                float nxr = fmaf(wr[n], xr[n], fmaf(-wi[n], xi[n], uu));
                float nxi = fmaf(wi[n], xr[n], wr[n] * xi[n]);
                xr[n] = nxr; xi[n] = nxi;
                acm[n & 3] = fmaf(kr[n], nxr, fmaf(-ki[n], nxi, acm[n & 3]));
            }
            float y = 2.0f * ((acm[0] + acm[1]) + (acm[2] + acm[3]));
            float ge = 0.5f * y * (1.0f + erff(y * 0.70710678118654752440f));
            ybuf[w * 4160 + (q * 4 + s) * 65 + c] = f2bf(ge);
        }
        ub = un;
    }
    __syncthreads();

    // ---- cooperative transpose-store: [b][hg][l][4 heads], 8B/lane coalesced
    unsigned short* __restrict__ Grow = Gout + ((size_t)(b * 64 + hg)) * L_ * 4;
    #pragma unroll 1
    for (int it = 0; it < 16; ++it) {
        int l = it * 256 + tid;
        int j = l & 63, cc = l >> 6;
        ushort4 pk;
        pk.x = ybuf[0 * 4160 + j * 65 + cc];
        pk.y = ybuf[1 * 4160 + j * 65 + cc];
        pk.z = ybuf[2 * 4160 + j * 65 + cc];
        pk.w = ybuf[3 * 4160 + j * 65 + cc];
        *(ushort4*)&Grow[(size_t)l * 4] = pk;
    }
}

// ---------------------------------------------------------------------------
// Kernel 2: out = (Wa*G + ba) * sigmoid(Wg*G + bg) via bf16 MFMA 16x16x32.
// Block: 256 thr (4 waves), tile = 64 op-pairs x 256 l, K = 256 (all of H).
// A (W) staged once in XOR-swizzled bf16 LDS; B (G) loaded per-lane straight
// from global in the transposed-blocked layout. GLU fused via LDS sigmoid tile.
// ---------------------------------------------------------------------------
__global__ __launch_bounds__(256, 2) void glu_gemm_kernel(
    const unsigned short* __restrict__ G,   // bf16 bits, [b][hg][l][4]
    const float* __restrict__ W,
    const float* __restrict__ bo,
    float* __restrict__ out)
{
    __shared__ __align__(16) unsigned char smem[65792];
    unsigned short* sW = (unsigned short*)smem;      // [128 m][32 granules] swizzled
    float* sGlu = (float*)smem;                      // [64][257] (reused after K-loop)

    const int tid  = threadIdx.x;
    const int lane = tid & 63;
    const int wave = tid >> 6;
    const int wm = wave >> 1, wn = wave & 1;

    const int l0 = blockIdx.x * 256;
    const int o0 = blockIdx.y * 64;
    const int b  = blockIdx.z;

    // ---- stage W -> bf16 LDS (XOR-swizzled 16B granules: g' = g ^ (row&31))
    {
        int r = tid >> 1;                    // 0..127 : m-row
        int half = tid & 1;                  // k-half
        int grow = (r < 64) ? (o0 + r) : (256 + o0 + (r - 64));
        const float* wp = W + (size_t)grow * 256 + half * 128;
        int rs = r & 31;
        #pragma unroll
        for (int q = 0; q < 16; ++q) {
            float4 f0 = *(const float4*)(wp + q * 8);
            float4 f1 = *(const float4*)(wp + q * 8 + 4);
            unsigned int p0 = f2bf(f0.x) | ((unsigned)f2bf(f0.y) << 16);
            unsigned int p1 = f2bf(f0.z) | ((unsigned)f2bf(f0.w) << 16);
            unsigned int p2 = f2bf(f1.x) | ((unsigned)f2bf(f1.y) << 16);
            unsigned int p3 = f2bf(f1.z) | ((unsigned)f2bf(f1.w) << 16);
            int gs = (half * 16 + q) ^ rs;
            uint4 val; val.x = p0; val.y = p1; val.z = p2; val.w = p3;
            *(uint4*)&sW[r * 256 + gs * 8] = val;
        }
    }
    __syncthreads();

    f32x4 acc[4][8];
    #pragma unroll
    for (int i = 0; i < 4; ++i)
        #pragma unroll
        for (int j = 0; j < 8; ++j) acc[i][j] = (f32x4){0.0f, 0.0f, 0.0f, 0.0f};

    const int ncol  = l0 + wn * 128 + (lane & 15);
    const int kgrp  = lane >> 4;             // 0..3 -> k-chunk (8 h's = 2 hg groups)
    const int mrow0 = wm * 64 + (lane & 15);

    ushort4 bl[2][8], bh[2][8];
    {
        size_t base = ((size_t)(b * 64 + kgrp * 2) * 4096 + ncol) * 4;
        #pragma unroll
        for (int nb = 0; nb < 8; ++nb) {
            bl[0][nb] = *(const ushort4*)(G + base + nb * 64);
            bh[0][nb] = *(const ushort4*)(G + base + 16384 + nb * 64);
        }
    }

    #pragma unroll
    for (int it = 0; it < 8; ++it) {
        int cur = it & 1;
        if (it < 7) {
            size_t base = ((size_t)(b * 64 + (it + 1) * 8 + kgrp * 2) * 4096 + ncol) * 4;
            #pragma unroll
            for (int nb = 0; nb < 8; ++nb) {
                bl[cur ^ 1][nb] = *(const ushort4*)(G + base + nb * 64);
                bh[cur ^ 1][nb] = *(const ushort4*)(G + base + 16384 + nb * 64);
            }
        }
        bf16x8 a[4];
        #pragma unroll
        for (int mi = 0; mi < 4; ++mi) {
            int r  = mrow0 + mi * 16;
            int gs = (it * 4 + kgrp) ^ (r & 31);
            a[mi] = *(const bf16x8*)&sW[r * 256 + gs * 8];
        }
        #pragma unroll
        for (int nb = 0; nb < 8; ++nb) {
            union { ushort4 u2[2]; bf16x8 v; } cb;
            cb.u2[0] = bl[cur][nb];
            cb.u2[1] = bh[cur][nb];
            bf16x8 bfr = cb.v;
            #pragma unroll
            for (int mi = 0; mi < 4; ++mi)
                acc[mi][nb] = __builtin_amdgcn_mfma_f32_16x16x32_bf16(a[mi], bfr, acc[mi][nb], 0, 0, 0);
        }
    }
    __syncthreads();   // sW dead; reuse as sGlu

    if (wm == 1) {     // g-waves: sigmoid(g + bg) -> LDS
        #pragma unroll
        for (int mi = 0; mi < 4; ++mi) {
            int gm0 = mi * 16 + (lane >> 4) * 4;
            #pragma unroll
            for (int nb = 0; nb < 8; ++nb) {
                int n = wn * 128 + nb * 16 + (lane & 15);
                #pragma unroll
                for (int r = 0; r < 4; ++r) {
                    float g = acc[mi][nb][r] + bo[256 + o0 + gm0 + r];
                    sGlu[(gm0 + r) * 257 + n] = 1.0f / (1.0f + expf(-g));
                }
            }
        }
    }
    __syncthreads();
    if (wm == 0) {     // a-waves: (a + ba) * sig -> out
        #pragma unroll
        for (int mi = 0; mi < 4; ++mi) {
            int am0 = mi * 16 + (lane >> 4) * 4;
            #pragma unroll
            for (int nb = 0; nb < 8; ++nb) {
                int n = wn * 128 + nb * 16 + (lane & 15);
                #pragma unroll
                for (int r = 0; r < 4; ++r) {
                    float a = acc[mi][nb][r] + bo[o0 + am0 + r];
                    out[((size_t)(b * 256 + o0 + am0 + r)) * 4096 + l0 + n] =
                        a * sGlu[(am0 + r) * 257 + n];
                }
            }
        }
    }
}

extern "C" void kernel_launch(void* const* d_in, const int* in_sizes, int n_in,
                              void* d_out, int out_size, void* d_ws, size_t ws_size,
                              hipStream_t stream) {
    (void)in_sizes; (void)n_in; (void)out_size;
    const float* hs     = (const float*)d_in[0];
    const float* log_dt = (const float*)d_in[1];
    const float* logA   = (const float*)d_in[2];
    const float* Aim    = (const float*)d_in[3];
    const float* Cre    = (const float*)d_in[4];
    const float* Cim    = (const float*)d_in[5];
    const float* Dp     = (const float*)d_in[6];
    const float* Wout   = (const float*)d_in[7];
    const float* bout   = (const float*)d_in[8];
    float* out          = (float*)d_out;
    unsigned short* G   = (unsigned short*)d_ws;   // bf16 bits

    if (ws_size < (size_t)B_ * H_ * L_ * 2) return;

    s4_scan_kernel<<<dim3(512), dim3(256), 0, stream>>>(
        hs, log_dt, logA, Aim, Cre, Cim, Dp, G);
    glu_gemm_kernel<<<dim3(16, 4, 8), dim3(256), 0, stream>>>(
        G, Wout, bout, out);
}

// Round 3
// 110.812 us; speedup vs baseline: 2.1137x; 1.1515x over previous
//
#include <hip/hip_runtime.h>
#include <hip/hip_bf16.h>

#define B_   8
#define H_   256
#define L_   4096
#define N2_  32

typedef __attribute__((ext_vector_type(8))) short bf16x8;
typedef __attribute__((ext_vector_type(4))) float f32x4;

__device__ __forceinline__ unsigned short f2bf(float x) {
    __hip_bfloat16 h = __float2bfloat16(x);
    unsigned short us;
    __builtin_memcpy(&us, &h, 2);
    return us;
}

union BF8 { ushort4 u4[2]; unsigned short s[8]; bf16x8 v; };

__device__ __forceinline__ float gelu_exact(float y) {
    return 0.5f * y * (1.0f + erff(y * 0.70710678118654752440f));
}

// ---------------------------------------------------------------------------
// Kernel 0 (prep): blocks 0..511 convert W -> bf16 pre-swizzled [ks][m][64];
// blocks 512..767 build per-head bf16 matrices P (end-state Vandermonde),
// Tk (lower-tri Toeplitz of conv taps), Q (state-correction rotation).
// ---------------------------------------------------------------------------
__global__ __launch_bounds__(64) void prep_kernel(
    const float* __restrict__ log_dt,
    const float* __restrict__ log_A_real,
    const float* __restrict__ A_imag,
    const float* __restrict__ C_re,
    const float* __restrict__ C_im,
    const float* __restrict__ W,
    unsigned short* __restrict__ MAT,
    unsigned short* __restrict__ W2)
{
    const int bid = blockIdx.x;
    const int t = threadIdx.x;
    if (bid < 512) {
        // W row m -> bf16, granule-XOR swizzled within each 64-k slice
        const int m = bid;
        const int ks = t >> 4, sub = t & 15;
        const int gr = sub >> 1, e4 = (sub & 1) * 4;
        const int klog = ks * 64 + ((gr ^ (m & 7)) << 3) + e4;
        float4 wv = *(const float4*)&W[m * 256 + klog];
        ushort4 o;
        o.x = f2bf(wv.x); o.y = f2bf(wv.y); o.z = f2bf(wv.z); o.w = f2bf(wv.w);
        *(ushort4*)&W2[ks * 32768 + m * 64 + gr * 8 + e4] = o;
        return;
    }
    __shared__ unsigned short sT[64 * 66];
    __shared__ float taps[64];
    const int h = bid - 512;
    unsigned short* __restrict__ Pd  = MAT + (size_t)h * 12288;
    unsigned short* __restrict__ Tkd = Pd + 4096;
    unsigned short* __restrict__ Qd  = Pd + 8192;
    const float dt = expf(log_dt[h]);

    // ---- P[2n][j] = Re(w_n^{63-j}), P[2n+1][j] = Im(w_n^{63-j}) ----
    {
        float pdt = dt * (float)(63 - t);
        #pragma unroll 4
        for (int n = 0; n < 32; ++n) {
            float Ar = -expf(log_A_real[h * 32 + n]);
            float Ai = A_imag[h * 32 + n];
            float mag = expf(pdt * Ar);
            float si, co; sincosf(pdt * Ai, &si, &co);
            sT[(2 * n) * 66 + t]     = f2bf(mag * co);
            sT[(2 * n + 1) * 66 + t] = f2bf(mag * si);
        }
    }
    __syncthreads();
    #pragma unroll
    for (int it = 0; it < 16; ++it) {
        int m = it * 4 + (t >> 4), c4 = (t & 15) * 4;
        ushort4 v;
        v.x = sT[m*66+c4]; v.y = sT[m*66+c4+1]; v.z = sT[m*66+c4+2]; v.w = sT[m*66+c4+3];
        *(ushort4*)&Pd[m * 64 + c4] = v;
    }
    __syncthreads();
    // ---- taps: k_j = sum_n Re(2*Ck_n * w_n^j), lane j = t ----
    {
        float kj = 0.0f;
        float jdt = dt * (float)t;
        #pragma unroll 4
        for (int n = 0; n < 32; ++n) {
            float Ar = -expf(log_A_real[h * 32 + n]);
            float Ai = A_imag[h * 32 + n];
            float Cr = C_re[h*32+n], Ci = C_im[h*32+n];
            float er = expf(dt*Ar); float s1, c1; sincosf(dt*Ai, &s1, &c1);
            float wr = er*c1, wi = er*s1;
            float den = Ar*Ar + Ai*Ai;
            float nr = wr - 1.0f, ni = wi;
            float qr = (nr*Ar + ni*Ai)/den, qi = (ni*Ar - nr*Ai)/den;
            float ck2r = 2.0f*(Cr*qr - Ci*qi), ck2i = 2.0f*(Cr*qi + Ci*qr);
            float mag = expf(jdt*Ar); float sj, cj; sincosf(jdt*Ai, &sj, &cj);
            kj = fmaf(ck2r, mag*cj, fmaf(-ck2i, mag*sj, kj));
        }
        taps[t] = kj;
    }
    __syncthreads();
    #pragma unroll
    for (int it = 0; it < 16; ++it) {
        int r = it * 4 + (t >> 4), c4 = (t & 15) * 4;
        ushort4 v;
        int d0 = r - c4;
        v.x = (d0     >= 0) ? f2bf(taps[d0])     : (unsigned short)0;
        v.y = (d0 - 1 >= 0) ? f2bf(taps[d0 - 1]) : (unsigned short)0;
        v.z = (d0 - 2 >= 0) ? f2bf(taps[d0 - 2]) : (unsigned short)0;
        v.w = (d0 - 3 >= 0) ? f2bf(taps[d0 - 3]) : (unsigned short)0;
        *(ushort4*)&Tkd[r * 64 + c4] = v;
    }
    // ---- Q: row j = t: Q[j][2n] = Re(2Ck w^{j+1}), Q[j][2n+1] = -Im ----
    {
        float j1dt = dt * (float)(t + 1);
        #pragma unroll 4
        for (int n = 0; n < 32; ++n) {
            float Ar = -expf(log_A_real[h * 32 + n]);
            float Ai = A_imag[h * 32 + n];
            float Cr = C_re[h*32+n], Ci = C_im[h*32+n];
            float er = expf(dt*Ar); float s1, c1; sincosf(dt*Ai, &s1, &c1);
            float wr = er*c1, wi = er*s1;
            float den = Ar*Ar + Ai*Ai;
            float nr = wr - 1.0f, ni = wi;
            float qr = (nr*Ar + ni*Ai)/den, qi = (ni*Ar - nr*Ai)/den;
            float ck2r = 2.0f*(Cr*qr - Ci*qi), ck2i = 2.0f*(Cr*qi + Ci*qr);
            float mag = expf(j1dt*Ar); float sq, cq; sincosf(j1dt*Ai, &sq, &cq);
            float wpr = mag*cq, wpi = mag*sq;
            float Qre = ck2r*wpr - ck2i*wpi;
            float Qim = ck2r*wpi + ck2i*wpr;
            sT[t * 66 + 2*n]     = f2bf(Qre);
            sT[t * 66 + 2*n + 1] = f2bf(-Qim);
        }
    }
    __syncthreads();
    #pragma unroll
    for (int it = 0; it < 16; ++it) {
        int m = it * 4 + (t >> 4), c4 = (t & 15) * 4;
        ushort4 v;
        v.x = sT[m*66+c4]; v.y = sT[m*66+c4+1]; v.z = sT[m*66+c4+2]; v.w = sT[m*66+c4+3];
        *(ushort4*)&Qd[m * 64 + c4] = v;
    }
}

// ---------------------------------------------------------------------------
// Kernel 1: MFMA-based chunked scan. Block = (b, hg=4 heads), wave = 1 head.
// Phase A: E = P*U (MFMA) -> LDS [c][m]. Phase B: serial 64-chunk scan (VALU,
// lanes 0..31, complex state per lane). Phase C: Y = Tk*U + Q*S (MFMA);
// epilogue adds D*u (fp32), exact GELU, bf16 -> ybuf. Phase E: transposed
// coalesced store to G[b][hg][l][4].
// ---------------------------------------------------------------------------
__global__ __launch_bounds__(256, 2) void s4_mfma_kernel(
    const float* __restrict__ u,
    const float* __restrict__ log_dt,
    const float* __restrict__ log_A_real,
    const float* __restrict__ A_imag,
    const float* __restrict__ Dp,
    const unsigned short* __restrict__ MAT,
    unsigned short* __restrict__ Gout)
{
    __shared__ __align__(16) unsigned char smem[4 * 17408];   // 68 KB
    const int tid  = threadIdx.x;
    const int w    = tid >> 6;
    const int lane = tid & 63;
    const int ln15 = lane & 15;
    const int hi4  = (lane >> 4) * 4;
    const int hi8  = (lane >> 4) * 8;
    const int bid  = blockIdx.x;
    const int b    = bid >> 6, hg = bid & 63;
    const int h    = hg * 4 + w;

    float* Eb = (float*)(smem + w * 17408);                    // [c][68] fp32
    unsigned short* yb = (unsigned short*)(smem + w * 17408);  // [c][68] bf16 overlay

    const float* __restrict__ urow = u + ((size_t)(b * H_ + h)) * L_;
    const unsigned short* __restrict__ Ph  = MAT + (size_t)h * 12288;
    const unsigned short* __restrict__ Tkh = Ph + 4096;
    const unsigned short* __restrict__ Qh  = Ph + 8192;

    // w^64 for the scan (lanes 0..31 use it)
    float wTr, wTi;
    {
        int n = lane & 31;
        float dt = expf(log_dt[h]);
        float Ar = -expf(log_A_real[h * 32 + n]);
        float Ai = A_imag[h * 32 + n];
        float er = expf(dt * Ar); float s, c; sincosf(dt * Ai, &s, &c);
        float pr = er * c, pi = er * s;
        #pragma unroll
        for (int k = 0; k < 6; ++k) { float a2 = pr*pr - pi*pi, b2 = 2.0f*pr*pi; pr = a2; pi = b2; }
        wTr = pr; wTi = pi;
    }

    // ---- Phase A: U fragments (kept for phase C) + E = P*U ----
    bf16x8 ufr[4][2];
    #pragma unroll
    for (int nt = 0; nt < 4; ++nt) {
        int c = nt * 16 + ln15;
        #pragma unroll
        for (int ks = 0; ks < 2; ++ks) {
            const float* p = urow + c * 64 + ks * 32 + hi8;
            float4 lo = *(const float4*)p;
            float4 hi = *(const float4*)(p + 4);
            BF8 t8;
            t8.s[0]=f2bf(lo.x); t8.s[1]=f2bf(lo.y); t8.s[2]=f2bf(lo.z); t8.s[3]=f2bf(lo.w);
            t8.s[4]=f2bf(hi.x); t8.s[5]=f2bf(hi.y); t8.s[6]=f2bf(hi.z); t8.s[7]=f2bf(hi.w);
            ufr[nt][ks] = t8.v;
        }
    }
    #pragma unroll
    for (int mt = 0; mt < 4; ++mt) {
        bf16x8 pa[2];
        #pragma unroll
        for (int ks = 0; ks < 2; ++ks)
            pa[ks] = *(const bf16x8*)&Ph[(mt * 16 + ln15) * 64 + ks * 32 + hi8];
        f32x4 e[4];
        #pragma unroll
        for (int nt = 0; nt < 4; ++nt) e[nt] = (f32x4){0.f, 0.f, 0.f, 0.f};
        #pragma unroll
        for (int ks = 0; ks < 2; ++ks)
            #pragma unroll
            for (int nt = 0; nt < 4; ++nt)
                e[nt] = __builtin_amdgcn_mfma_f32_16x16x32_bf16(pa[ks], ufr[nt][ks], e[nt], 0, 0, 0);
        #pragma unroll
        for (int nt = 0; nt < 4; ++nt)
            *(f32x4*)&Eb[(nt * 16 + ln15) * 68 + mt * 16 + hi4] = e[nt];
    }
    __syncthreads();

    // ---- Phase B: serial scan over 64 chunks; leaves INCOMING state S[c] ----
    if (lane < 32) {
        int n2 = 2 * lane;
        float Xr = 0.0f, Xi = 0.0f;
        float2 e = *(float2*)&Eb[n2];
        #pragma unroll 4
        for (int c = 0; c < 64; ++c) {
            float2 en = e;
            if (c < 63) en = *(float2*)&Eb[(c + 1) * 68 + n2];
            *(float2*)&Eb[c * 68 + n2] = make_float2(Xr, Xi);
            float nXr = fmaf(wTr, Xr, fmaf(-wTi, Xi, e.x));
            float nXi = fmaf(wTi, Xr, fmaf( wTr, Xi, e.y));
            Xr = nXr; Xi = nXi; e = en;
        }
    }
    __syncthreads();

    // ---- Phase C: load S fragments, Y = Tk*U + Q*S, fused epilogue ----
    bf16x8 sfr[4][2];
    #pragma unroll
    for (int nt = 0; nt < 4; ++nt) {
        int c = nt * 16 + ln15;
        #pragma unroll
        for (int ks = 0; ks < 2; ++ks) {
            float4 lo = *(const float4*)&Eb[c * 68 + ks * 32 + hi8];
            float4 hi = *(const float4*)&Eb[c * 68 + ks * 32 + hi8 + 4];
            BF8 t8;
            t8.s[0]=f2bf(lo.x); t8.s[1]=f2bf(lo.y); t8.s[2]=f2bf(lo.z); t8.s[3]=f2bf(lo.w);
            t8.s[4]=f2bf(hi.x); t8.s[5]=f2bf(hi.y); t8.s[6]=f2bf(hi.z); t8.s[7]=f2bf(hi.w);
            sfr[nt][ks] = t8.v;
        }
    }
    const float Dh = Dp[h];
    #pragma unroll
    for (int mt = 0; mt < 4; ++mt) {
        bf16x8 ta[2], qa[2];
        #pragma unroll
        for (int ks = 0; ks < 2; ++ks) {
            ta[ks] = *(const bf16x8*)&Tkh[(mt * 16 + ln15) * 64 + ks * 32 + hi8];
            qa[ks] = *(const bf16x8*)&Qh [(mt * 16 + ln15) * 64 + ks * 32 + hi8];
        }
        #pragma unroll
        for (int nt = 0; nt < 4; ++nt) {
            f32x4 a = (f32x4){0.f, 0.f, 0.f, 0.f};
            #pragma unroll
            for (int ks = 0; ks < 2; ++ks) {
                a = __builtin_amdgcn_mfma_f32_16x16x32_bf16(ta[ks], ufr[nt][ks], a, 0, 0, 0);
                a = __builtin_amdgcn_mfma_f32_16x16x32_bf16(qa[ks], sfr[nt][ks], a, 0, 0, 0);
            }
            int c  = nt * 16 + ln15;
            int j0 = mt * 16 + hi4;
            float4 uu = *(const float4*)&urow[c * 64 + j0];
            ushort4 o;
            o.x = f2bf(gelu_exact(a[0] + Dh * uu.x));
            o.y = f2bf(gelu_exact(a[1] + Dh * uu.y));
            o.z = f2bf(gelu_exact(a[2] + Dh * uu.z));
            o.w = f2bf(gelu_exact(a[3] + Dh * uu.w));
            *(ushort4*)&yb[c * 68 + j0] = o;
        }
    }
    __syncthreads();

    // ---- Phase E: coalesced transposed store -> G[b][hg][l][4] ----
    unsigned short* __restrict__ Grow = Gout + ((size_t)(b * 64 + hg)) * (L_ * 4);
    #pragma unroll
    for (int it = 0; it < 16; ++it) {
        int l = it * 256 + tid;
        int c = l >> 6, j = l & 63;
        ushort4 pk;
        pk.x = ((unsigned short*)(smem + 0 * 17408))[c * 68 + j];
        pk.y = ((unsigned short*)(smem + 1 * 17408))[c * 68 + j];
        pk.z = ((unsigned short*)(smem + 2 * 17408))[c * 68 + j];
        pk.w = ((unsigned short*)(smem + 3 * 17408))[c * 68 + j];
        *(ushort4*)&Grow[(size_t)l * 4] = pk;
    }
}

// ---------------------------------------------------------------------------
// Kernel 2: out = (Wa*G + ba) * sigmoid(Wg*G + bg). 256 blocks x 512 thr.
// Block tile M=512 (a & g rows interleaved per wave -> in-register GLU),
// N=128 l. W staged per-64-k slice in XOR-swizzled bf16 LDS; G per-lane
// direct from global ([b][hg][l][4] layout).
// ---------------------------------------------------------------------------
__global__ __launch_bounds__(512, 2) void glu_gemm_kernel(
    const unsigned short* __restrict__ G,
    const unsigned short* __restrict__ W2,
    const float* __restrict__ bo,
    float* __restrict__ out)
{
    __shared__ __align__(16) unsigned short sW[32768];   // 64 KB: [512 m][64 k]
    const int tid  = threadIdx.x;
    const int lane = tid & 63;
    const int wv   = tid >> 6;
    const int ln15 = lane & 15;
    const int hi   = lane >> 4;
    const int l0   = blockIdx.x * 128;
    const int b    = blockIdx.y;

    f32x4 acc[4][8];
    #pragma unroll
    for (int i = 0; i < 4; ++i)
        #pragma unroll
        for (int j = 0; j < 8; ++j) acc[i][j] = (f32x4){0.f, 0.f, 0.f, 0.f};

    int mrow[4];
    mrow[0] = wv * 32 + ln15;
    mrow[1] = wv * 32 + 16 + ln15;
    mrow[2] = 256 + wv * 32 + ln15;
    mrow[3] = 256 + wv * 32 + 16 + ln15;

    uint4 stg[8];
    #pragma unroll
    for (int i = 0; i < 8; ++i)
        stg[i] = *(const uint4*)&W2[i * 4096 + tid * 8];

    for (int ks = 0; ks < 4; ++ks) {
        __syncthreads();
        #pragma unroll
        for (int i = 0; i < 8; ++i)
            *(uint4*)&sW[i * 4096 + tid * 8] = stg[i];
        if (ks < 3) {
            #pragma unroll
            for (int i = 0; i < 8; ++i)
                stg[i] = *(const uint4*)&W2[(ks + 1) * 32768 + i * 4096 + tid * 8];
        }
        __syncthreads();
        #pragma unroll
        for (int ksub = 0; ksub < 2; ++ksub) {
            bf16x8 af[4];
            #pragma unroll
            for (int mt = 0; mt < 4; ++mt) {
                int m = mrow[mt];
                int gl = ksub * 4 + hi;
                af[mt] = *(const bf16x8*)((const unsigned char*)sW + m * 128 + ((gl ^ (m & 7)) << 4));
            }
            int kk  = ks * 64 + ksub * 32 + hi * 8;
            int hg0 = kk >> 2;
            #pragma unroll
            for (int nb = 0; nb < 8; ++nb) {
                int col = l0 + nb * 16 + ln15;
                size_t base = ((size_t)(b * 64 + hg0) * 4096 + col) * 4;
                BF8 bf;
                bf.u4[0] = *(const ushort4*)&G[base];
                bf.u4[1] = *(const ushort4*)&G[base + 16384];
                #pragma unroll
                for (int mt = 0; mt < 4; ++mt)
                    acc[mt][nb] = __builtin_amdgcn_mfma_f32_16x16x32_bf16(af[mt], bf.v, acc[mt][nb], 0, 0, 0);
            }
        }
    }
    // ---- in-register GLU epilogue ----
    #pragma unroll
    for (int mt = 0; mt < 2; ++mt) {
        int rowbase = wv * 32 + mt * 16 + hi * 4;
        float4 ba = *(const float4*)&bo[rowbase];
        float4 bg = *(const float4*)&bo[256 + rowbase];
        #pragma unroll
        for (int nb = 0; nb < 8; ++nb) {
            int col = l0 + nb * 16 + ln15;
            #pragma unroll
            for (int rr = 0; rr < 4; ++rr) {
                float a = acc[mt][nb][rr]     + ((const float*)&ba)[rr];
                float g = acc[mt + 2][nb][rr] + ((const float*)&bg)[rr];
                float sg = 1.0f / (1.0f + expf(-g));
                out[((size_t)(b * 256 + rowbase + rr)) * 4096 + col] = a * sg;
            }
        }
    }
}

extern "C" void kernel_launch(void* const* d_in, const int* in_sizes, int n_in,
                              void* d_out, int out_size, void* d_ws, size_t ws_size,
                              hipStream_t stream) {
    (void)in_sizes; (void)n_in; (void)out_size;
    const float* hs     = (const float*)d_in[0];
    const float* log_dt = (const float*)d_in[1];
    const float* logA   = (const float*)d_in[2];
    const float* Aim    = (const float*)d_in[3];
    const float* Cre    = (const float*)d_in[4];
    const float* Cim    = (const float*)d_in[5];
    const float* Dp     = (const float*)d_in[6];
    const float* Wout   = (const float*)d_in[7];
    const float* bout   = (const float*)d_in[8];
    float* out          = (float*)d_out;

    unsigned short* G   = (unsigned short*)d_ws;                           // 16 MB
    unsigned short* MAT = (unsigned short*)((char*)d_ws + 16777216);       // 6.29 MB
    unsigned short* W2  = (unsigned short*)((char*)d_ws + 23068672);       // 256 KB

    if (ws_size < (size_t)23330816) return;

    prep_kernel<<<dim3(768), dim3(64), 0, stream>>>(
        log_dt, logA, Aim, Cre, Cim, Wout, MAT, W2);
    s4_mfma_kernel<<<dim3(512), dim3(256), 0, stream>>>(
        hs, log_dt, logA, Aim, Dp, MAT, G);
    glu_gemm_kernel<<<dim3(32, 8), dim3(512), 0, stream>>>(
        G, W2, bout, out);
}

// Round 4
// 87.295 us; speedup vs baseline: 2.6831x; 1.2694x over previous
//
#include <hip/hip_runtime.h>
#include <hip/hip_bf16.h>

#define B_   8
#define H_   256
#define L_   4096
#define N2_  32

typedef __attribute__((ext_vector_type(8))) short bf16x8;
typedef __attribute__((ext_vector_type(4))) float f32x4;

__device__ __forceinline__ unsigned short f2bf(float x) {
    __hip_bfloat16 h = __float2bfloat16(x);
    unsigned short us;
    __builtin_memcpy(&us, &h, 2);
    return us;
}

union BF8 { ushort4 u4[2]; unsigned short s[8]; bf16x8 v; };

__device__ __forceinline__ float gelu_exact(float y) {
    return 0.5f * y * (1.0f + erff(y * 0.70710678118654752440f));
}

// ---------------------------------------------------------------------------
// Kernel 0 (prep): blocks 0..511 convert W -> bf16 pre-swizzled [ks][m][64];
// blocks 512..767 build per-head bf16 matrices P (end-state Vandermonde),
// Tk (lower-tri Toeplitz of conv taps), Q (state-correction rotation).
// ---------------------------------------------------------------------------
__global__ __launch_bounds__(64) void prep_kernel(
    const float* __restrict__ log_dt,
    const float* __restrict__ log_A_real,
    const float* __restrict__ A_imag,
    const float* __restrict__ C_re,
    const float* __restrict__ C_im,
    const float* __restrict__ W,
    unsigned short* __restrict__ MAT,
    unsigned short* __restrict__ W2)
{
    const int bid = blockIdx.x;
    const int t = threadIdx.x;
    if (bid < 512) {
        // W row m -> bf16, granule-XOR swizzled within each 64-k slice
        const int m = bid;
        const int ks = t >> 4, sub = t & 15;
        const int gr = sub >> 1, e4 = (sub & 1) * 4;
        const int klog = ks * 64 + ((gr ^ (m & 7)) << 3) + e4;
        float4 wv = *(const float4*)&W[m * 256 + klog];
        ushort4 o;
        o.x = f2bf(wv.x); o.y = f2bf(wv.y); o.z = f2bf(wv.z); o.w = f2bf(wv.w);
        *(ushort4*)&W2[ks * 32768 + m * 64 + gr * 8 + e4] = o;
        return;
    }
    __shared__ unsigned short sT[64 * 66];
    __shared__ float taps[64];
    const int h = bid - 512;
    unsigned short* __restrict__ Pd  = MAT + (size_t)h * 12288;
    unsigned short* __restrict__ Tkd = Pd + 4096;
    unsigned short* __restrict__ Qd  = Pd + 8192;
    const float dt = expf(log_dt[h]);

    // ---- P[2n][j] = Re(w_n^{63-j}), P[2n+1][j] = Im(w_n^{63-j}) ----
    {
        float pdt = dt * (float)(63 - t);
        #pragma unroll 4
        for (int n = 0; n < 32; ++n) {
            float Ar = -expf(log_A_real[h * 32 + n]);
            float Ai = A_imag[h * 32 + n];
            float mag = expf(pdt * Ar);
            float si, co; sincosf(pdt * Ai, &si, &co);
            sT[(2 * n) * 66 + t]     = f2bf(mag * co);
            sT[(2 * n + 1) * 66 + t] = f2bf(mag * si);
        }
    }
    __syncthreads();
    #pragma unroll
    for (int it = 0; it < 16; ++it) {
        int m = it * 4 + (t >> 4), c4 = (t & 15) * 4;
        ushort4 v;
        v.x = sT[m*66+c4]; v.y = sT[m*66+c4+1]; v.z = sT[m*66+c4+2]; v.w = sT[m*66+c4+3];
        *(ushort4*)&Pd[m * 64 + c4] = v;
    }
    __syncthreads();
    // ---- taps: k_j = sum_n Re(2*Ck_n * w_n^j), lane j = t ----
    {
        float kj = 0.0f;
        float jdt = dt * (float)t;
        #pragma unroll 4
        for (int n = 0; n < 32; ++n) {
            float Ar = -expf(log_A_real[h * 32 + n]);
            float Ai = A_imag[h * 32 + n];
            float Cr = C_re[h*32+n], Ci = C_im[h*32+n];
            float er = expf(dt*Ar); float s1, c1; sincosf(dt*Ai, &s1, &c1);
            float wr = er*c1, wi = er*s1;
            float den = Ar*Ar + Ai*Ai;
            float nr = wr - 1.0f, ni = wi;
            float qr = (nr*Ar + ni*Ai)/den, qi = (ni*Ar - nr*Ai)/den;
            float ck2r = 2.0f*(Cr*qr - Ci*qi), ck2i = 2.0f*(Cr*qi + Ci*qr);
            float mag = expf(jdt*Ar); float sj, cj; sincosf(jdt*Ai, &sj, &cj);
            kj = fmaf(ck2r, mag*cj, fmaf(-ck2i, mag*sj, kj));
        }
        taps[t] = kj;
    }
    __syncthreads();
    #pragma unroll
    for (int it = 0; it < 16; ++it) {
        int r = it * 4 + (t >> 4), c4 = (t & 15) * 4;
        ushort4 v;
        int d0 = r - c4;
        v.x = (d0     >= 0) ? f2bf(taps[d0])     : (unsigned short)0;
        v.y = (d0 - 1 >= 0) ? f2bf(taps[d0 - 1]) : (unsigned short)0;
        v.z = (d0 - 2 >= 0) ? f2bf(taps[d0 - 2]) : (unsigned short)0;
        v.w = (d0 - 3 >= 0) ? f2bf(taps[d0 - 3]) : (unsigned short)0;
        *(ushort4*)&Tkd[r * 64 + c4] = v;
    }
    // ---- Q: row j = t: Q[j][2n] = Re(2Ck w^{j+1}), Q[j][2n+1] = -Im ----
    {
        float j1dt = dt * (float)(t + 1);
        #pragma unroll 4
        for (int n = 0; n < 32; ++n) {
            float Ar = -expf(log_A_real[h * 32 + n]);
            float Ai = A_imag[h * 32 + n];
            float Cr = C_re[h*32+n], Ci = C_im[h*32+n];
            float er = expf(dt*Ar); float s1, c1; sincosf(dt*Ai, &s1, &c1);
            float wr = er*c1, wi = er*s1;
            float den = Ar*Ar + Ai*Ai;
            float nr = wr - 1.0f, ni = wi;
            float qr = (nr*Ar + ni*Ai)/den, qi = (ni*Ar - nr*Ai)/den;
            float ck2r = 2.0f*(Cr*qr - Ci*qi), ck2i = 2.0f*(Cr*qi + Ci*qr);
            float mag = expf(j1dt*Ar); float sq, cq; sincosf(j1dt*Ai, &sq, &cq);
            float wpr = mag*cq, wpi = mag*sq;
            float Qre = ck2r*wpr - ck2i*wpi;
            float Qim = ck2r*wpi + ck2i*wpr;
            sT[t * 66 + 2*n]     = f2bf(Qre);
            sT[t * 66 + 2*n + 1] = f2bf(-Qim);
        }
    }
    __syncthreads();
    #pragma unroll
    for (int it = 0; it < 16; ++it) {
        int m = it * 4 + (t >> 4), c4 = (t & 15) * 4;
        ushort4 v;
        v.x = sT[m*66+c4]; v.y = sT[m*66+c4+1]; v.z = sT[m*66+c4+2]; v.w = sT[m*66+c4+3];
        *(ushort4*)&Qd[m * 64 + c4] = v;
    }
}

// ---------------------------------------------------------------------------
// Kernel 1: MFMA-based chunked scan (unchanged from round 3).
// ---------------------------------------------------------------------------
__global__ __launch_bounds__(256, 2) void s4_mfma_kernel(
    const float* __restrict__ u,
    const float* __restrict__ log_dt,
    const float* __restrict__ log_A_real,
    const float* __restrict__ A_imag,
    const float* __restrict__ Dp,
    const unsigned short* __restrict__ MAT,
    unsigned short* __restrict__ Gout)
{
    __shared__ __align__(16) unsigned char smem[4 * 17408];   // 68 KB
    const int tid  = threadIdx.x;
    const int w    = tid >> 6;
    const int lane = tid & 63;
    const int ln15 = lane & 15;
    const int hi4  = (lane >> 4) * 4;
    const int hi8  = (lane >> 4) * 8;
    const int bid  = blockIdx.x;
    const int b    = bid >> 6, hg = bid & 63;
    const int h    = hg * 4 + w;

    float* Eb = (float*)(smem + w * 17408);                    // [c][68] fp32
    unsigned short* yb = (unsigned short*)(smem + w * 17408);  // [c][68] bf16 overlay

    const float* __restrict__ urow = u + ((size_t)(b * H_ + h)) * L_;
    const unsigned short* __restrict__ Ph  = MAT + (size_t)h * 12288;
    const unsigned short* __restrict__ Tkh = Ph + 4096;
    const unsigned short* __restrict__ Qh  = Ph + 8192;

    // w^64 for the scan (lanes 0..31 use it)
    float wTr, wTi;
    {
        int n = lane & 31;
        float dt = expf(log_dt[h]);
        float Ar = -expf(log_A_real[h * 32 + n]);
        float Ai = A_imag[h * 32 + n];
        float er = expf(dt * Ar); float s, c; sincosf(dt * Ai, &s, &c);
        float pr = er * c, pi = er * s;
        #pragma unroll
        for (int k = 0; k < 6; ++k) { float a2 = pr*pr - pi*pi, b2 = 2.0f*pr*pi; pr = a2; pi = b2; }
        wTr = pr; wTi = pi;
    }

    // ---- Phase A: U fragments (kept for phase C) + E = P*U ----
    bf16x8 ufr[4][2];
    #pragma unroll
    for (int nt = 0; nt < 4; ++nt) {
        int c = nt * 16 + ln15;
        #pragma unroll
        for (int ks = 0; ks < 2; ++ks) {
            const float* p = urow + c * 64 + ks * 32 + hi8;
            float4 lo = *(const float4*)p;
            float4 hi = *(const float4*)(p + 4);
            BF8 t8;
            t8.s[0]=f2bf(lo.x); t8.s[1]=f2bf(lo.y); t8.s[2]=f2bf(lo.z); t8.s[3]=f2bf(lo.w);
            t8.s[4]=f2bf(hi.x); t8.s[5]=f2bf(hi.y); t8.s[6]=f2bf(hi.z); t8.s[7]=f2bf(hi.w);
            ufr[nt][ks] = t8.v;
        }
    }
    #pragma unroll
    for (int mt = 0; mt < 4; ++mt) {
        bf16x8 pa[2];
        #pragma unroll
        for (int ks = 0; ks < 2; ++ks)
            pa[ks] = *(const bf16x8*)&Ph[(mt * 16 + ln15) * 64 + ks * 32 + hi8];
        f32x4 e[4];
        #pragma unroll
        for (int nt = 0; nt < 4; ++nt) e[nt] = (f32x4){0.f, 0.f, 0.f, 0.f};
        #pragma unroll
        for (int ks = 0; ks < 2; ++ks)
            #pragma unroll
            for (int nt = 0; nt < 4; ++nt)
                e[nt] = __builtin_amdgcn_mfma_f32_16x16x32_bf16(pa[ks], ufr[nt][ks], e[nt], 0, 0, 0);
        #pragma unroll
        for (int nt = 0; nt < 4; ++nt)
            *(f32x4*)&Eb[(nt * 16 + ln15) * 68 + mt * 16 + hi4] = e[nt];
    }
    __syncthreads();

    // ---- Phase B: serial scan over 64 chunks; leaves INCOMING state S[c] ----
    if (lane < 32) {
        int n2 = 2 * lane;
        float Xr = 0.0f, Xi = 0.0f;
        float2 e = *(float2*)&Eb[n2];
        #pragma unroll 4
        for (int c = 0; c < 64; ++c) {
            float2 en = e;
            if (c < 63) en = *(float2*)&Eb[(c + 1) * 68 + n2];
            *(float2*)&Eb[c * 68 + n2] = make_float2(Xr, Xi);
            float nXr = fmaf(wTr, Xr, fmaf(-wTi, Xi, e.x));
            float nXi = fmaf(wTi, Xr, fmaf( wTr, Xi, e.y));
            Xr = nXr; Xi = nXi; e = en;
        }
    }
    __syncthreads();

    // ---- Phase C: load S fragments, Y = Tk*U + Q*S, fused epilogue ----
    bf16x8 sfr[4][2];
    #pragma unroll
    for (int nt = 0; nt < 4; ++nt) {
        int c = nt * 16 + ln15;
        #pragma unroll
        for (int ks = 0; ks < 2; ++ks) {
            float4 lo = *(const float4*)&Eb[c * 68 + ks * 32 + hi8];
            float4 hi = *(const float4*)&Eb[c * 68 + ks * 32 + hi8 + 4];
            BF8 t8;
            t8.s[0]=f2bf(lo.x); t8.s[1]=f2bf(lo.y); t8.s[2]=f2bf(lo.z); t8.s[3]=f2bf(lo.w);
            t8.s[4]=f2bf(hi.x); t8.s[5]=f2bf(hi.y); t8.s[6]=f2bf(hi.z); t8.s[7]=f2bf(hi.w);
            sfr[nt][ks] = t8.v;
        }
    }
    const float Dh = Dp[h];
    #pragma unroll
    for (int mt = 0; mt < 4; ++mt) {
        bf16x8 ta[2], qa[2];
        #pragma unroll
        for (int ks = 0; ks < 2; ++ks) {
            ta[ks] = *(const bf16x8*)&Tkh[(mt * 16 + ln15) * 64 + ks * 32 + hi8];
            qa[ks] = *(const bf16x8*)&Qh [(mt * 16 + ln15) * 64 + ks * 32 + hi8];
        }
        #pragma unroll
        for (int nt = 0; nt < 4; ++nt) {
            f32x4 a = (f32x4){0.f, 0.f, 0.f, 0.f};
            #pragma unroll
            for (int ks = 0; ks < 2; ++ks) {
                a = __builtin_amdgcn_mfma_f32_16x16x32_bf16(ta[ks], ufr[nt][ks], a, 0, 0, 0);
                a = __builtin_amdgcn_mfma_f32_16x16x32_bf16(qa[ks], sfr[nt][ks], a, 0, 0, 0);
            }
            int c  = nt * 16 + ln15;
            int j0 = mt * 16 + hi4;
            float4 uu = *(const float4*)&urow[c * 64 + j0];
            ushort4 o;
            o.x = f2bf(gelu_exact(a[0] + Dh * uu.x));
            o.y = f2bf(gelu_exact(a[1] + Dh * uu.y));
            o.z = f2bf(gelu_exact(a[2] + Dh * uu.z));
            o.w = f2bf(gelu_exact(a[3] + Dh * uu.w));
            *(ushort4*)&yb[c * 68 + j0] = o;
        }
    }
    __syncthreads();

    // ---- Phase E: coalesced transposed store -> G[b][hg][l][4] ----
    unsigned short* __restrict__ Grow = Gout + ((size_t)(b * 64 + hg)) * (L_ * 4);
    #pragma unroll
    for (int it = 0; it < 16; ++it) {
        int l = it * 256 + tid;
        int c = l >> 6, j = l & 63;
        ushort4 pk;
        pk.x = ((unsigned short*)(smem + 0 * 17408))[c * 68 + j];
        pk.y = ((unsigned short*)(smem + 1 * 17408))[c * 68 + j];
        pk.z = ((unsigned short*)(smem + 2 * 17408))[c * 68 + j];
        pk.w = ((unsigned short*)(smem + 3 * 17408))[c * 68 + j];
        *(ushort4*)&Grow[(size_t)l * 4] = pk;
    }
}

// ---------------------------------------------------------------------------
// Kernel 2 (restructured): out = (Wa*G + ba) * sigmoid(Wg*G + bg).
// Grid 64x2x8 = 1024 blocks of 256 thr (4 waves), 4 blocks/CU target.
// Block tile: 128 GLU pairs (M=256) x 64 l. W staged in 32KB XOR-swizzled
// LDS per 64-k slice; B (G) register double-buffered from global.
// Epilogue: GLU in-register -> stride-36 LDS tile -> full-line float4 stores.
// ---------------------------------------------------------------------------
__global__ __launch_bounds__(256, 4) void glu_gemm_kernel(
    const unsigned short* __restrict__ G,
    const unsigned short* __restrict__ W2,
    const float* __restrict__ bo,
    float* __restrict__ out)
{
    __shared__ __align__(16) unsigned char smem[36864];  // 36 KB
    unsigned short* sW = (unsigned short*)smem;          // [256 rows][64 k] swizzled

    const int tid  = threadIdx.x;
    const int lane = tid & 63;
    const int wv   = tid >> 6;         // 0..3
    const int wm   = wv >> 1;          // 0..1 (m-half within block)
    const int wn   = wv & 1;           // 0..1 (n-half)
    const int ln15 = lane & 15;
    const int hi   = lane >> 4;        // 0..3

    const int l0 = blockIdx.x * 64;
    const int m0 = blockIdx.y * 128;   // 0 or 128 (GLU-pair offset)
    const int b  = blockIdx.z;
    const int col0 = l0 + wn * 32 + ln15;

    f32x4 acc[8][2];
    #pragma unroll
    for (int i = 0; i < 8; ++i)
        #pragma unroll
        for (int j = 0; j < 2; ++j) acc[i][j] = (f32x4){0.f, 0.f, 0.f, 0.f};

    BF8 bb[2][2];
    auto loadB = [&](int ksub, BF8* dst) {
        int hg0 = ksub * 8 + hi * 2;
        size_t base = ((size_t)(b * 64 + hg0) * 4096 + col0) * 4;
        dst[0].u4[0] = *(const ushort4*)&G[base];
        dst[0].u4[1] = *(const ushort4*)&G[base + 16384];
        dst[1].u4[0] = *(const ushort4*)&G[base + 64];
        dst[1].u4[1] = *(const ushort4*)&G[base + 16384 + 64];
    };
    loadB(0, bb[0]);

    for (int ksub = 0; ksub < 8; ++ksub) {
        if ((ksub & 1) == 0) {
            const int ks = ksub >> 1;
            __syncthreads();
            // stage rows [m0, m0+128) (a) and [256+m0, 256+m0+128) (g), slice ks
            const unsigned short* src1 = W2 + (size_t)ks * 32768 + m0 * 64;
            const unsigned short* src2 = W2 + (size_t)ks * 32768 + (256 + m0) * 64;
            uint4 t[8];
            #pragma unroll
            for (int i = 0; i < 4; ++i) t[i]     = *(const uint4*)&src1[i * 2048 + tid * 8];
            #pragma unroll
            for (int i = 0; i < 4; ++i) t[4 + i] = *(const uint4*)&src2[i * 2048 + tid * 8];
            #pragma unroll
            for (int i = 0; i < 8; ++i)
                *(uint4*)&sW[i * 2048 + tid * 8] = t[i];
            __syncthreads();
        }
        if (ksub < 7) loadB(ksub + 1, bb[(ksub + 1) & 1]);
        const BF8* bc = bb[ksub & 1];
        const int gl = (ksub & 1) * 4 + hi;
        #pragma unroll
        for (int half = 0; half < 2; ++half) {
            bf16x8 af[4];
            #pragma unroll
            for (int mt = 0; mt < 4; ++mt) {
                int r = half * 128 + wm * 64 + mt * 16 + ln15;
                af[mt] = *(const bf16x8*)((const unsigned char*)sW + r * 128 + ((gl ^ (r & 7)) << 4));
            }
            #pragma unroll
            for (int mt = 0; mt < 4; ++mt)
                #pragma unroll
                for (int nb = 0; nb < 2; ++nb)
                    acc[half * 4 + mt][nb] =
                        __builtin_amdgcn_mfma_f32_16x16x32_bf16(af[mt], bc[nb].v,
                                                                acc[half * 4 + mt][nb], 0, 0, 0);
        }
    }

    // ---- epilogue: in-register GLU -> per-wave LDS [64][36] -> coalesced out
    __syncthreads();                     // all sW reads done; reuse as sEp
    float* sEp = (float*)smem + wv * 2304;   // 64*36 floats per wave
    #pragma unroll
    for (int mt = 0; mt < 4; ++mt) {
        int r0 = mt * 16 + hi * 4;       // local a-row base
        float4 ba = *(const float4*)&bo[m0 + wm * 64 + r0];
        float4 bg = *(const float4*)&bo[256 + m0 + wm * 64 + r0];
        #pragma unroll
        for (int nb = 0; nb < 2; ++nb) {
            #pragma unroll
            for (int rr = 0; rr < 4; ++rr) {
                float a = acc[mt][nb][rr]     + ((const float*)&ba)[rr];
                float g = acc[4 + mt][nb][rr] + ((const float*)&bg)[rr];
                sEp[(r0 + rr) * 36 + nb * 16 + ln15] = a / (1.0f + expf(-g));
            }
        }
    }
    __syncthreads();
    {
        const int rl = lane >> 3;        // 0..7
        const int c4 = (lane & 7) * 4;   // 0..28
        float* obase = out + ((size_t)(b * 256 + m0 + wm * 64)) * 4096 + l0 + wn * 32;
        #pragma unroll
        for (int ps = 0; ps < 8; ++ps) {
            int row = ps * 8 + rl;
            float4 v = *(const float4*)&sEp[row * 36 + c4];
            *(float4*)&obase[(size_t)row * 4096 + c4] = v;
        }
    }
}

extern "C" void kernel_launch(void* const* d_in, const int* in_sizes, int n_in,
                              void* d_out, int out_size, void* d_ws, size_t ws_size,
                              hipStream_t stream) {
    (void)in_sizes; (void)n_in; (void)out_size;
    const float* hs     = (const float*)d_in[0];
    const float* log_dt = (const float*)d_in[1];
    const float* logA   = (const float*)d_in[2];
    const float* Aim    = (const float*)d_in[3];
    const float* Cre    = (const float*)d_in[4];
    const float* Cim    = (const float*)d_in[5];
    const float* Dp     = (const float*)d_in[6];
    const float* Wout   = (const float*)d_in[7];
    const float* bout   = (const float*)d_in[8];
    float* out          = (float*)d_out;

    unsigned short* G   = (unsigned short*)d_ws;                           // 16 MB
    unsigned short* MAT = (unsigned short*)((char*)d_ws + 16777216);       // 6.29 MB
    unsigned short* W2  = (unsigned short*)((char*)d_ws + 23068672);       // 256 KB

    if (ws_size < (size_t)23330816) return;

    prep_kernel<<<dim3(768), dim3(64), 0, stream>>>(
        log_dt, logA, Aim, Cre, Cim, Wout, MAT, W2);
    s4_mfma_kernel<<<dim3(512), dim3(256), 0, stream>>>(
        hs, log_dt, logA, Aim, Dp, MAT, G);
    glu_gemm_kernel<<<dim3(64, 2, 8), dim3(256), 0, stream>>>(
        G, W2, bout, out);
}

// Round 5
// 57.466 us; speedup vs baseline: 4.0759x; 1.5191x over previous
//
#include <hip/hip_runtime.h>
#include <hip/hip_bf16.h>

#define B_   8
#define H_   256
#define L_   4096
#define N2_  32

typedef __attribute__((ext_vector_type(8))) short bf16x8;
typedef __attribute__((ext_vector_type(4))) float f32x4;

__device__ __forceinline__ unsigned short f2bf(float x) {
    __hip_bfloat16 h = __float2bfloat16(x);
    unsigned short us;
    __builtin_memcpy(&us, &h, 2);
    return us;
}

union BF8 { ushort4 u4[2]; unsigned short s[8]; bf16x8 v; };

__device__ __forceinline__ float gelu_exact(float y) {
    return 0.5f * y * (1.0f + erff(y * 0.70710678118654752440f));
}

// hw sin/cos with explicit revolution reduction (v_sin_f32 takes revolutions)
__device__ __forceinline__ void fast_sincos(float x, float* s, float* c) {
    float rev = x * 0.15915494309189535f;
    rev = rev - floorf(rev);
    *s = __builtin_amdgcn_sinf(rev);
    *c = __builtin_amdgcn_cosf(rev);
}

// ---------------------------------------------------------------------------
// Kernel 0 (prep, parallelized): blocks 0..255 = one head each (256 thr):
// build P (end-state Vandermonde), Tk (lower-tri Toeplitz of taps), Q
// (state-correction rotation) in bf16. Blocks 256..383: W -> bf16 swizzled.
// ---------------------------------------------------------------------------
__global__ __launch_bounds__(256) void prep_kernel(
    const float* __restrict__ log_dt,
    const float* __restrict__ log_A_real,
    const float* __restrict__ A_imag,
    const float* __restrict__ C_re,
    const float* __restrict__ C_im,
    const float* __restrict__ W,
    unsigned short* __restrict__ MAT,
    unsigned short* __restrict__ W2)
{
    const int bid = blockIdx.x;
    const int tid = threadIdx.x;
    if (bid >= 256) {
        // W row m -> bf16, granule-XOR swizzled within each 64-k slice
        int gq = (bid - 256) * 256 + tid;        // 0..32767
        int m = gq >> 6, t = gq & 63;
        int ks = t >> 4, sub = t & 15;
        int gr = sub >> 1, e4 = (sub & 1) * 4;
        int klog = ks * 64 + ((gr ^ (m & 7)) << 3) + e4;
        float4 wv = *(const float4*)&W[m * 256 + klog];
        ushort4 o;
        o.x = f2bf(wv.x); o.y = f2bf(wv.y); o.z = f2bf(wv.z); o.w = f2bf(wv.w);
        *(ushort4*)&W2[ks * 32768 + m * 64 + gr * 8 + e4] = o;
        return;
    }
    const int h    = bid;
    const int j    = tid & 63;
    const int part = tid >> 6;                   // 0..3 -> 8 n's each

    __shared__ float sAr[32], sAi[32], sK2r[32], sK2i[32];
    __shared__ float sTap[4][64];
    __shared__ unsigned short sQ[64 * 68];

    unsigned short* __restrict__ Pd  = MAT + (size_t)h * 12288;
    unsigned short* __restrict__ Tkd = Pd + 4096;
    unsigned short* __restrict__ Qd  = Pd + 8192;
    const float dt = __expf(log_dt[h]);

    if (tid < 32) {
        int n = tid;
        float Ar = -__expf(log_A_real[h * 32 + n]);
        float Ai = A_imag[h * 32 + n];
        float er = __expf(dt * Ar);
        float s, c; fast_sincos(dt * Ai, &s, &c);
        float wr = er * c, wi = er * s;
        float Cr = C_re[h * 32 + n], Ci = C_im[h * 32 + n];
        float den = Ar * Ar + Ai * Ai;
        float nr = wr - 1.0f, ni = wi;
        float qr = (nr * Ar + ni * Ai) / den;
        float qi = (ni * Ar - nr * Ai) / den;
        sAr[n] = Ar; sAi[n] = Ai;
        sK2r[n] = 2.0f * (Cr * qr - Ci * qi);
        sK2i[n] = 2.0f * (Cr * qi + Ci * qr);
    }
    __syncthreads();

    // ---- P[2n][j] = Re(w_n^{63-j}), P[2n+1][j] = Im (direct coalesced) ----
    {
        float pdt = dt * (float)(63 - j);
        #pragma unroll
        for (int q = 0; q < 8; ++q) {
            int n = part * 8 + q;
            float mag = __expf(pdt * sAr[n]);
            float s, c; fast_sincos(pdt * sAi[n], &s, &c);
            Pd[(2 * n)     * 64 + j] = f2bf(mag * c);
            Pd[(2 * n + 1) * 64 + j] = f2bf(mag * s);
        }
    }
    // ---- taps partial sums + Q staging ----
    {
        float jdt = dt * (float)j;
        float acc = 0.0f;
        #pragma unroll
        for (int q = 0; q < 8; ++q) {
            int n = part * 8 + q;
            float mag = __expf(jdt * sAr[n]);
            float s, c; fast_sincos(jdt * sAi[n], &s, &c);
            acc = fmaf(sK2r[n], mag * c, fmaf(-sK2i[n], mag * s, acc));
        }
        sTap[part][j] = acc;
        float j1dt = dt * (float)(j + 1);
        #pragma unroll
        for (int q = 0; q < 8; ++q) {
            int n = part * 8 + q;
            float mag = __expf(j1dt * sAr[n]);
            float s, c; fast_sincos(j1dt * sAi[n], &s, &c);
            float wpr = mag * c, wpi = mag * s;
            sQ[j * 68 + 2 * n]     = f2bf(sK2r[n] * wpr - sK2i[n] * wpi);
            sQ[j * 68 + 2 * n + 1] = f2bf(-(sK2r[n] * wpi + sK2i[n] * wpr));
        }
    }
    __syncthreads();
    if (part == 0)
        sTap[0][j] = sTap[0][j] + sTap[1][j] + sTap[2][j] + sTap[3][j];
    __syncthreads();

    // ---- Tk[r][c] = taps[r-c] (r>=c) ----
    {
        int r  = tid >> 2;
        int c0 = (tid & 3) * 16;
        #pragma unroll
        for (int cc = 0; cc < 16; cc += 4) {
            int c = c0 + cc;
            ushort4 v;
            v.x = (r - c     >= 0) ? f2bf(sTap[0][r - c])     : (unsigned short)0;
            v.y = (r - c - 1 >= 0) ? f2bf(sTap[0][r - c - 1]) : (unsigned short)0;
            v.z = (r - c - 2 >= 0) ? f2bf(sTap[0][r - c - 2]) : (unsigned short)0;
            v.w = (r - c - 3 >= 0) ? f2bf(sTap[0][r - c - 3]) : (unsigned short)0;
            *(ushort4*)&Tkd[r * 64 + c] = v;
        }
    }
    // ---- Q cooperative coalesced store ----
    #pragma unroll
    for (int it = 0; it < 4; ++it) {
        int quad = it * 256 + tid;
        int row = quad >> 4, c4 = (quad & 15) * 4;
        ushort4 v;
        v.x = sQ[row * 68 + c4];     v.y = sQ[row * 68 + c4 + 1];
        v.z = sQ[row * 68 + c4 + 2]; v.w = sQ[row * 68 + c4 + 3];
        *(ushort4*)&Qd[row * 64 + c4] = v;
    }
}

// ---------------------------------------------------------------------------
// Kernel 1: MFMA-based chunked scan (unchanged).
// ---------------------------------------------------------------------------
__global__ __launch_bounds__(256, 2) void s4_mfma_kernel(
    const float* __restrict__ u,
    const float* __restrict__ log_dt,
    const float* __restrict__ log_A_real,
    const float* __restrict__ A_imag,
    const float* __restrict__ Dp,
    const unsigned short* __restrict__ MAT,
    unsigned short* __restrict__ Gout)
{
    __shared__ __align__(16) unsigned char smem[4 * 17408];   // 68 KB
    const int tid  = threadIdx.x;
    const int w    = tid >> 6;
    const int lane = tid & 63;
    const int ln15 = lane & 15;
    const int hi4  = (lane >> 4) * 4;
    const int hi8  = (lane >> 4) * 8;
    const int bid  = blockIdx.x;
    const int b    = bid >> 6, hg = bid & 63;
    const int h    = hg * 4 + w;

    float* Eb = (float*)(smem + w * 17408);                    // [c][68] fp32
    unsigned short* yb = (unsigned short*)(smem + w * 17408);  // [c][68] bf16 overlay

    const float* __restrict__ urow = u + ((size_t)(b * H_ + h)) * L_;
    const unsigned short* __restrict__ Ph  = MAT + (size_t)h * 12288;
    const unsigned short* __restrict__ Tkh = Ph + 4096;
    const unsigned short* __restrict__ Qh  = Ph + 8192;

    // w^64 for the scan (lanes 0..31 use it)
    float wTr, wTi;
    {
        int n = lane & 31;
        float dt = expf(log_dt[h]);
        float Ar = -expf(log_A_real[h * 32 + n]);
        float Ai = A_imag[h * 32 + n];
        float er = expf(dt * Ar); float s, c; sincosf(dt * Ai, &s, &c);
        float pr = er * c, pi = er * s;
        #pragma unroll
        for (int k = 0; k < 6; ++k) { float a2 = pr*pr - pi*pi, b2 = 2.0f*pr*pi; pr = a2; pi = b2; }
        wTr = pr; wTi = pi;
    }

    // ---- Phase A: U fragments (kept for phase C) + E = P*U ----
    bf16x8 ufr[4][2];
    #pragma unroll
    for (int nt = 0; nt < 4; ++nt) {
        int c = nt * 16 + ln15;
        #pragma unroll
        for (int ks = 0; ks < 2; ++ks) {
            const float* p = urow + c * 64 + ks * 32 + hi8;
            float4 lo = *(const float4*)p;
            float4 hi = *(const float4*)(p + 4);
            BF8 t8;
            t8.s[0]=f2bf(lo.x); t8.s[1]=f2bf(lo.y); t8.s[2]=f2bf(lo.z); t8.s[3]=f2bf(lo.w);
            t8.s[4]=f2bf(hi.x); t8.s[5]=f2bf(hi.y); t8.s[6]=f2bf(hi.z); t8.s[7]=f2bf(hi.w);
            ufr[nt][ks] = t8.v;
        }
    }
    #pragma unroll
    for (int mt = 0; mt < 4; ++mt) {
        bf16x8 pa[2];
        #pragma unroll
        for (int ks = 0; ks < 2; ++ks)
            pa[ks] = *(const bf16x8*)&Ph[(mt * 16 + ln15) * 64 + ks * 32 + hi8];
        f32x4 e[4];
        #pragma unroll
        for (int nt = 0; nt < 4; ++nt) e[nt] = (f32x4){0.f, 0.f, 0.f, 0.f};
        #pragma unroll
        for (int ks = 0; ks < 2; ++ks)
            #pragma unroll
            for (int nt = 0; nt < 4; ++nt)
                e[nt] = __builtin_amdgcn_mfma_f32_16x16x32_bf16(pa[ks], ufr[nt][ks], e[nt], 0, 0, 0);
        #pragma unroll
        for (int nt = 0; nt < 4; ++nt)
            *(f32x4*)&Eb[(nt * 16 + ln15) * 68 + mt * 16 + hi4] = e[nt];
    }
    __syncthreads();

    // ---- Phase B: serial scan over 64 chunks; leaves INCOMING state S[c] ----
    if (lane < 32) {
        int n2 = 2 * lane;
        float Xr = 0.0f, Xi = 0.0f;
        float2 e = *(float2*)&Eb[n2];
        #pragma unroll 4
        for (int c = 0; c < 64; ++c) {
            float2 en = e;
            if (c < 63) en = *(float2*)&Eb[(c + 1) * 68 + n2];
            *(float2*)&Eb[c * 68 + n2] = make_float2(Xr, Xi);
            float nXr = fmaf(wTr, Xr, fmaf(-wTi, Xi, e.x));
            float nXi = fmaf(wTi, Xr, fmaf( wTr, Xi, e.y));
            Xr = nXr; Xi = nXi; e = en;
        }
    }
    __syncthreads();

    // ---- Phase C: load S fragments, Y = Tk*U + Q*S, fused epilogue ----
    bf16x8 sfr[4][2];
    #pragma unroll
    for (int nt = 0; nt < 4; ++nt) {
        int c = nt * 16 + ln15;
        #pragma unroll
        for (int ks = 0; ks < 2; ++ks) {
            float4 lo = *(const float4*)&Eb[c * 68 + ks * 32 + hi8];
            float4 hi = *(const float4*)&Eb[c * 68 + ks * 32 + hi8 + 4];
            BF8 t8;
            t8.s[0]=f2bf(lo.x); t8.s[1]=f2bf(lo.y); t8.s[2]=f2bf(lo.z); t8.s[3]=f2bf(lo.w);
            t8.s[4]=f2bf(hi.x); t8.s[5]=f2bf(hi.y); t8.s[6]=f2bf(hi.z); t8.s[7]=f2bf(hi.w);
            sfr[nt][ks] = t8.v;
        }
    }
    const float Dh = Dp[h];
    #pragma unroll
    for (int mt = 0; mt < 4; ++mt) {
        bf16x8 ta[2], qa[2];
        #pragma unroll
        for (int ks = 0; ks < 2; ++ks) {
            ta[ks] = *(const bf16x8*)&Tkh[(mt * 16 + ln15) * 64 + ks * 32 + hi8];
            qa[ks] = *(const bf16x8*)&Qh [(mt * 16 + ln15) * 64 + ks * 32 + hi8];
        }
        #pragma unroll
        for (int nt = 0; nt < 4; ++nt) {
            f32x4 a = (f32x4){0.f, 0.f, 0.f, 0.f};
            #pragma unroll
            for (int ks = 0; ks < 2; ++ks) {
                a = __builtin_amdgcn_mfma_f32_16x16x32_bf16(ta[ks], ufr[nt][ks], a, 0, 0, 0);
                a = __builtin_amdgcn_mfma_f32_16x16x32_bf16(qa[ks], sfr[nt][ks], a, 0, 0, 0);
            }
            int c  = nt * 16 + ln15;
            int j0 = mt * 16 + hi4;
            float4 uu = *(const float4*)&urow[c * 64 + j0];
            ushort4 o;
            o.x = f2bf(gelu_exact(a[0] + Dh * uu.x));
            o.y = f2bf(gelu_exact(a[1] + Dh * uu.y));
            o.z = f2bf(gelu_exact(a[2] + Dh * uu.z));
            o.w = f2bf(gelu_exact(a[3] + Dh * uu.w));
            *(ushort4*)&yb[c * 68 + j0] = o;
        }
    }
    __syncthreads();

    // ---- Phase E: coalesced transposed store -> G[b][hg][l][4] ----
    unsigned short* __restrict__ Grow = Gout + ((size_t)(b * 64 + hg)) * (L_ * 4);
    #pragma unroll
    for (int it = 0; it < 16; ++it) {
        int l = it * 256 + tid;
        int c = l >> 6, j = l & 63;
        ushort4 pk;
        pk.x = ((unsigned short*)(smem + 0 * 17408))[c * 68 + j];
        pk.y = ((unsigned short*)(smem + 1 * 17408))[c * 68 + j];
        pk.z = ((unsigned short*)(smem + 2 * 17408))[c * 68 + j];
        pk.w = ((unsigned short*)(smem + 3 * 17408))[c * 68 + j];
        *(ushort4*)&Grow[(size_t)l * 4] = pk;
    }
}

// ---------------------------------------------------------------------------
// Kernel 2: out = (Wa*G + ba) * sigmoid(Wg*G + bg)  (unchanged from round 4).
// ---------------------------------------------------------------------------
__global__ __launch_bounds__(256, 4) void glu_gemm_kernel(
    const unsigned short* __restrict__ G,
    const unsigned short* __restrict__ W2,
    const float* __restrict__ bo,
    float* __restrict__ out)
{
    __shared__ __align__(16) unsigned char smem[36864];  // 36 KB
    unsigned short* sW = (unsigned short*)smem;          // [256 rows][64 k] swizzled

    const int tid  = threadIdx.x;
    const int lane = tid & 63;
    const int wv   = tid >> 6;         // 0..3
    const int wm   = wv >> 1;          // 0..1 (m-half within block)
    const int wn   = wv & 1;           // 0..1 (n-half)
    const int ln15 = lane & 15;
    const int hi   = lane >> 4;        // 0..3

    const int l0 = blockIdx.x * 64;
    const int m0 = blockIdx.y * 128;   // 0 or 128 (GLU-pair offset)
    const int b  = blockIdx.z;
    const int col0 = l0 + wn * 32 + ln15;

    f32x4 acc[8][2];
    #pragma unroll
    for (int i = 0; i < 8; ++i)
        #pragma unroll
        for (int j = 0; j < 2; ++j) acc[i][j] = (f32x4){0.f, 0.f, 0.f, 0.f};

    BF8 bb[2][2];
    auto loadB = [&](int ksub, BF8* dst) {
        int hg0 = ksub * 8 + hi * 2;
        size_t base = ((size_t)(b * 64 + hg0) * 4096 + col0) * 4;
        dst[0].u4[0] = *(const ushort4*)&G[base];
        dst[0].u4[1] = *(const ushort4*)&G[base + 16384];
        dst[1].u4[0] = *(const ushort4*)&G[base + 64];
        dst[1].u4[1] = *(const ushort4*)&G[base + 16384 + 64];
    };
    loadB(0, bb[0]);

    for (int ksub = 0; ksub < 8; ++ksub) {
        if ((ksub & 1) == 0) {
            const int ks = ksub >> 1;
            __syncthreads();
            const unsigned short* src1 = W2 + (size_t)ks * 32768 + m0 * 64;
            const unsigned short* src2 = W2 + (size_t)ks * 32768 + (256 + m0) * 64;
            uint4 t[8];
            #pragma unroll
            for (int i = 0; i < 4; ++i) t[i]     = *(const uint4*)&src1[i * 2048 + tid * 8];
            #pragma unroll
            for (int i = 0; i < 4; ++i) t[4 + i] = *(const uint4*)&src2[i * 2048 + tid * 8];
            #pragma unroll
            for (int i = 0; i < 8; ++i)
                *(uint4*)&sW[i * 2048 + tid * 8] = t[i];
            __syncthreads();
        }
        if (ksub < 7) loadB(ksub + 1, bb[(ksub + 1) & 1]);
        const BF8* bc = bb[ksub & 1];
        const int gl = (ksub & 1) * 4 + hi;
        #pragma unroll
        for (int half = 0; half < 2; ++half) {
            bf16x8 af[4];
            #pragma unroll
            for (int mt = 0; mt < 4; ++mt) {
                int r = half * 128 + wm * 64 + mt * 16 + ln15;
                af[mt] = *(const bf16x8*)((const unsigned char*)sW + r * 128 + ((gl ^ (r & 7)) << 4));
            }
            #pragma unroll
            for (int mt = 0; mt < 4; ++mt)
                #pragma unroll
                for (int nb = 0; nb < 2; ++nb)
                    acc[half * 4 + mt][nb] =
                        __builtin_amdgcn_mfma_f32_16x16x32_bf16(af[mt], bc[nb].v,
                                                                acc[half * 4 + mt][nb], 0, 0, 0);
        }
    }

    // ---- epilogue: in-register GLU -> per-wave LDS [64][36] -> coalesced out
    __syncthreads();
    float* sEp = (float*)smem + wv * 2304;   // 64*36 floats per wave
    #pragma unroll
    for (int mt = 0; mt < 4; ++mt) {
        int r0 = mt * 16 + hi * 4;
        float4 ba = *(const float4*)&bo[m0 + wm * 64 + r0];
        float4 bg = *(const float4*)&bo[256 + m0 + wm * 64 + r0];
        #pragma unroll
        for (int nb = 0; nb < 2; ++nb) {
            #pragma unroll
            for (int rr = 0; rr < 4; ++rr) {
                float a = acc[mt][nb][rr]     + ((const float*)&ba)[rr];
                float g = acc[4 + mt][nb][rr] + ((const float*)&bg)[rr];
                sEp[(r0 + rr) * 36 + nb * 16 + ln15] = a / (1.0f + expf(-g));
            }
        }
    }
    __syncthreads();
    {
        const int rl = lane >> 3;
        const int c4 = (lane & 7) * 4;
        float* obase = out + ((size_t)(b * 256 + m0 + wm * 64)) * 4096 + l0 + wn * 32;
        #pragma unroll
        for (int ps = 0; ps < 8; ++ps) {
            int row = ps * 8 + rl;
            float4 v = *(const float4*)&sEp[row * 36 + c4];
            *(float4*)&obase[(size_t)row * 4096 + c4] = v;
        }
    }
}

extern "C" void kernel_launch(void* const* d_in, const int* in_sizes, int n_in,
                              void* d_out, int out_size, void* d_ws, size_t ws_size,
                              hipStream_t stream) {
    (void)in_sizes; (void)n_in; (void)out_size;
    const float* hs     = (const float*)d_in[0];
    const float* log_dt = (const float*)d_in[1];
    const float* logA   = (const float*)d_in[2];
    const float* Aim    = (const float*)d_in[3];
    const float* Cre    = (const float*)d_in[4];
    const float* Cim    = (const float*)d_in[5];
    const float* Dp     = (const float*)d_in[6];
    const float* Wout   = (const float*)d_in[7];
    const float* bout   = (const float*)d_in[8];
    float* out          = (float*)d_out;

    unsigned short* G   = (unsigned short*)d_ws;                           // 16 MB
    unsigned short* MAT = (unsigned short*)((char*)d_ws + 16777216);       // 6.29 MB
    unsigned short* W2  = (unsigned short*)((char*)d_ws + 23068672);       // 256 KB

    if (ws_size < (size_t)23330816) return;

    prep_kernel<<<dim3(384), dim3(256), 0, stream>>>(
        log_dt, logA, Aim, Cre, Cim, Wout, MAT, W2);
    s4_mfma_kernel<<<dim3(512), dim3(256), 0, stream>>>(
        hs, log_dt, logA, Aim, Dp, MAT, G);
    glu_gemm_kernel<<<dim3(64, 2, 8), dim3(256), 0, stream>>>(
        G, W2, bout, out);
}